// Round 1
// baseline (680.873 us; speedup 1.0000x reference)
//
#include <hip/hip_runtime.h>

// Problem constants (match reference)
#define BATCH 8192
#define TSTEPS 200
#define FEAT 16
#define HID 32
#define GATES 128   // 4*HID, Keras order: i | f | cc | o
#define DOUT 60
#define MPW 4       // batch elements per wave (1 wave per block)

// sigmoid via raw v_exp_f32 / v_rcp_f32 (≤2 ulp, fine vs 8.7e-3 threshold)
__device__ __forceinline__ float fast_sigmoid(float v) {
    float e = __builtin_amdgcn_exp2f(v * -1.44269504088896340736f);
    return __builtin_amdgcn_rcpf(1.0f + e);
}

// Persistent-RNN layout:
//   lane j owns gate columns j and j+64 of the fused [48 x 128] weight matrix,
//   kept in VGPRs for the whole kernel. Batch index is wave-uniform: x_t is a
//   uniform (scalar) load, h is broadcast from a wave-private LDS buffer.
//   lane j<32: (i_u, cc_u) for unit u=j ; lane j+32: (f_u, o_u).
__global__ __launch_bounds__(64) void lstm_fused(
    const float* __restrict__ x,    // [B, T, F]
    const float* __restrict__ W,    // [F, 128]
    const float* __restrict__ U,    // [H, 128]
    const float* __restrict__ bg,   // [128]
    const float* __restrict__ W1,   // [H, 60]
    const float* __restrict__ b1,   // [60]
    const float* __restrict__ W2,   // [H, 60]
    const float* __restrict__ b2,   // [60]
    float* __restrict__ out)        // [2 * B * 60] (long || lat)
{
    const int lane = threadIdx.x;          // 0..63
    const int blk  = blockIdx.x;           // 0..BATCH/MPW-1
    const int b0   = blk * MPW;

    __shared__ __align__(16) float hsh[MPW][HID];   // hidden state, wave-private

    // ---- stationary weights: columns j0 = lane, j1 = lane + 64 ----
    const int j0 = lane;
    const int j1 = lane + 64;
    float wx0[FEAT], wx1[FEAT], wh0[HID], wh1[HID];
    #pragma unroll
    for (int k = 0; k < FEAT; k++) {
        wx0[k] = W[k * GATES + j0];
        wx1[k] = W[k * GATES + j1];
    }
    #pragma unroll
    for (int k = 0; k < HID; k++) {
        wh0[k] = U[k * GATES + j0];
        wh1[k] = U[k * GATES + j1];
    }
    const float bb0 = bg[j0];
    const float bb1 = bg[j1];

    const int  u  = lane & 31;
    const bool lo = (lane < 32);

    float c[MPW];
    #pragma unroll
    for (int m = 0; m < MPW; m++) c[m] = 0.0f;
    if (lo) {
        #pragma unroll
        for (int m = 0; m < MPW; m++) hsh[m][u] = 0.0f;
    }

    const float* xbase = x + (size_t)b0 * TSTEPS * FEAT;

    for (int t = 0; t < TSTEPS; t++) {
        #pragma unroll
        for (int m = 0; m < MPW; m++) {
            // ---- gate pre-activations: acc = b + W^T x_t + U^T h ----
            const float4* xp = reinterpret_cast<const float4*>(
                xbase + ((size_t)m * TSTEPS + t) * FEAT);
            float acc0 = bb0, acc1 = bb1;
            #pragma unroll
            for (int kk = 0; kk < FEAT / 4; kk++) {
                float4 xv = xp[kk];   // wave-uniform address -> scalar load
                acc0 = fmaf(xv.x, wx0[kk*4+0], acc0);
                acc1 = fmaf(xv.x, wx1[kk*4+0], acc1);
                acc0 = fmaf(xv.y, wx0[kk*4+1], acc0);
                acc1 = fmaf(xv.y, wx1[kk*4+1], acc1);
                acc0 = fmaf(xv.z, wx0[kk*4+2], acc0);
                acc1 = fmaf(xv.z, wx1[kk*4+2], acc1);
                acc0 = fmaf(xv.w, wx0[kk*4+3], acc0);
                acc1 = fmaf(xv.w, wx1[kk*4+3], acc1);
            }
            #pragma unroll
            for (int kk = 0; kk < HID / 4; kk++) {
                // uniform LDS address -> conflict-free broadcast ds_read_b128
                float4 hv = *reinterpret_cast<const float4*>(&hsh[m][kk*4]);
                acc0 = fmaf(hv.x, wh0[kk*4+0], acc0);
                acc1 = fmaf(hv.x, wh1[kk*4+0], acc1);
                acc0 = fmaf(hv.y, wh0[kk*4+1], acc0);
                acc1 = fmaf(hv.y, wh1[kk*4+1], acc1);
                acc0 = fmaf(hv.z, wh0[kk*4+2], acc0);
                acc1 = fmaf(hv.z, wh1[kk*4+2], acc1);
                acc0 = fmaf(hv.w, wh0[kk*4+3], acc0);
                acc1 = fmaf(hv.w, wh1[kk*4+3], acc1);
            }

            // ---- activations (branchless where possible) ----
            // lanes <32: acc0 = i (sigmoid), acc1 = cc (relu)
            // lanes>=32: acc0 = f (sigmoid), acc1 = o  (sigmoid)
            float a0 = fast_sigmoid(acc0);
            float s1 = fast_sigmoid(acc1);
            float r1 = fmaxf(acc1, 0.0f);
            float a1 = lo ? r1 : s1;

            // recombine across the half-wave: low lanes fetch f_s, o_s
            float f_s = __shfl_xor(a0, 32, 64);
            float o_s = __shfl_xor(a1, 32, 64);

            if (lo) {
                float cn = fmaf(f_s, c[m], a0 * a1);  // f*c + i*relu(cc)
                c[m] = cn;
                float hn = o_s * fmaxf(cn, 0.0f);     // o * relu(c_new)
                hsh[m][u] = hn;
            }
        }
    }

    // ---- heads: long = h W1 + b1 ; lat = h W2 + b2 ; lane j = output col ----
    if (lane < DOUT) {
        float w1c[HID], w2c[HID];
        #pragma unroll
        for (int k = 0; k < HID; k++) {
            w1c[k] = W1[k * DOUT + lane];
            w2c[k] = W2[k * DOUT + lane];
        }
        const float bo1 = b1[lane];
        const float bo2 = b2[lane];
        #pragma unroll
        for (int m = 0; m < MPW; m++) {
            float s1 = bo1, s2 = bo2;
            #pragma unroll
            for (int k = 0; k < HID; k++) {
                float hv = hsh[m][k];
                s1 = fmaf(hv, w1c[k], s1);
                s2 = fmaf(hv, w2c[k], s2);
            }
            out[(size_t)(b0 + m) * DOUT + lane] = s1;
            out[(size_t)BATCH * DOUT + (size_t)(b0 + m) * DOUT + lane] = s2;
        }
    }
}

extern "C" void kernel_launch(void* const* d_in, const int* in_sizes, int n_in,
                              void* d_out, int out_size, void* d_ws, size_t ws_size,
                              hipStream_t stream) {
    const float* x  = (const float*)d_in[0];
    const float* W  = (const float*)d_in[1];
    const float* U  = (const float*)d_in[2];
    const float* bg = (const float*)d_in[3];
    const float* W1 = (const float*)d_in[4];
    const float* b1 = (const float*)d_in[5];
    const float* W2 = (const float*)d_in[6];
    const float* b2 = (const float*)d_in[7];
    float* out = (float*)d_out;

    dim3 grid(BATCH / MPW);   // 2048 one-wave blocks -> 2 waves/SIMD chip-wide
    dim3 block(64);
    lstm_fused<<<grid, block, 0, stream>>>(x, W, U, bg, W1, b1, W2, b2, out);
}